// Round 4
// baseline (1515.880 us; speedup 1.0000x reference)
//
#include <hip/hip_runtime.h>

#define HID 256
#define VOC 50257
#define NTOK 4096
#define NCT3 393                  // ceil(VOC / 128)
#define CG 8                      // column groups (== XCDs)
#define LN_EPS 1e-3f
#define PROB_ELEMS 205852672      // 4096 * 50257

typedef __attribute__((ext_vector_type(8))) short bf16x8;
typedef __attribute__((ext_vector_type(4))) float f32x4;
typedef __attribute__((ext_vector_type(16))) float f32x16;

__device__ inline unsigned short f2bf(float f) {
    unsigned int u = __builtin_bit_cast(unsigned int, f);
    unsigned int r = u + 0x7FFFu + ((u >> 16) & 1u);
    return (unsigned short)(r >> 16);
}
__device__ inline float bf2f(unsigned short b) {
    unsigned int u = ((unsigned int)b) << 16;
    return __builtin_bit_cast(float, u);
}

// ---------------------------------------------------------------- conv f32->bf16
__global__ void conv_f32_bf16(const float* __restrict__ src,
                              unsigned short* __restrict__ dst, int n4) {
    int i = blockIdx.x * blockDim.x + threadIdx.x;
    int stride = gridDim.x * blockDim.x;
    for (; i < n4; i += stride) {
        float4 v = reinterpret_cast<const float4*>(src)[i];
        ushort4 o;
        o.x = f2bf(v.x); o.y = f2bf(v.y); o.z = f2bf(v.z); o.w = f2bf(v.w);
        reinterpret_cast<ushort4*>(dst)[i] = o;
    }
}

// ---------------------------------------------------------------- W transpose: W[e][k][h] f32 -> Wt[e*256+h][k] bf16
__global__ __launch_bounds__(256) void wt_transpose(
    const float* __restrict__ Wsh, const float* __restrict__ Wsp,
    unsigned short* __restrict__ Wtbf) {
    __shared__ float t[64][65];
    int gcol0 = blockIdx.x * 64;
    int k0 = blockIdx.y * 64;
    int e = gcol0 >> 8, h0 = gcol0 & 255;
    const float* Wp = (e < 2) ? (Wsh + e * 65536) : (Wsp + (e - 2) * 65536);
    int tid = threadIdx.x;
#pragma unroll
    for (int i = 0; i < 16; ++i) {
        int id = tid + i * 256;
        int k = id >> 6, h = id & 63;
        t[k][h] = Wp[(k0 + k) * 256 + h0 + h];
    }
    __syncthreads();
#pragma unroll
    for (int i = 0; i < 4; ++i) {
        int id = tid + i * 256;
        int h = id >> 4, kq = id & 15;
        ushort4 o;
        o.x = f2bf(t[kq * 4 + 0][h]); o.y = f2bf(t[kq * 4 + 1][h]);
        o.z = f2bf(t[kq * 4 + 2][h]); o.w = f2bf(t[kq * 4 + 3][h]);
        *reinterpret_cast<ushort4*>(Wtbf + (size_t)(gcol0 + h) * 256 + k0 + kq * 4) = o;
    }
}

// ---------------------------------------------------------------- expert GEMM
__global__ __launch_bounds__(256) void expert_gemm(
    const unsigned short* __restrict__ xbf,
    const unsigned short* __restrict__ Wtbf,
    const float* __restrict__ bsh, const float* __restrict__ bsp,
    float* __restrict__ cexp) {
    __shared__ unsigned short sA[64 * 256];
    __shared__ unsigned short sB[128 * 256];
    int bid = blockIdx.x;
    int rt = bid & 63;
    int ct = bid >> 6;
    int row0 = rt * 64, col0 = ct * 128;
    int tid = threadIdx.x;

#pragma unroll
    for (int i = 0; i < 8; ++i) {
        int id = tid + i * 256;
        int r = id >> 5, c = id & 31;
        bf16x8 v = *reinterpret_cast<const bf16x8*>(xbf + (row0 + r) * 256 + c * 8);
        *reinterpret_cast<bf16x8*>(sA + r * 256 + ((c ^ (r & 7)) * 8)) = v;
    }
#pragma unroll
    for (int i = 0; i < 16; ++i) {
        int id = tid + i * 256;
        int j = id >> 5, c = id & 31;
        bf16x8 v = *reinterpret_cast<const bf16x8*>(Wtbf + (size_t)(col0 + j) * 256 + c * 8);
        *reinterpret_cast<bf16x8*>(sB + j * 256 + ((c ^ (j & 7)) * 8)) = v;
    }
    __syncthreads();

    int lane = tid & 63, wave = tid >> 6;
    int wcol = wave * 32;
    int lrow = lane & 15, g = lane >> 4;
    f32x4 zero4 = {0.f, 0.f, 0.f, 0.f};
    f32x4 acc[4][2];
#pragma unroll
    for (int mf = 0; mf < 4; ++mf)
#pragma unroll
        for (int nf = 0; nf < 2; ++nf) acc[mf][nf] = zero4;

#pragma unroll
    for (int ks = 0; ks < 8; ++ks) {
        int kc = ks * 4 + g;
        bf16x8 a[4], b[2];
#pragma unroll
        for (int mf = 0; mf < 4; ++mf) {
            int r = mf * 16 + lrow;
            a[mf] = *reinterpret_cast<const bf16x8*>(sA + r * 256 + ((kc ^ (r & 7)) * 8));
        }
#pragma unroll
        for (int nf = 0; nf < 2; ++nf) {
            int j = wcol + nf * 16 + lrow;
            b[nf] = *reinterpret_cast<const bf16x8*>(sB + j * 256 + ((kc ^ (j & 7)) * 8));
        }
#pragma unroll
        for (int mf = 0; mf < 4; ++mf)
#pragma unroll
            for (int nf = 0; nf < 2; ++nf)
                acc[mf][nf] = __builtin_amdgcn_mfma_f32_16x16x32_bf16(a[mf], b[nf], acc[mf][nf], 0, 0, 0);
    }

#pragma unroll
    for (int nf = 0; nf < 2; ++nf) {
        int col = col0 + wcol + nf * 16 + lrow;
        int e = col >> 8, h = col & 255;
        float bias = (e < 2) ? bsh[e * 256 + h] : bsp[(e - 2) * 256 + h];
#pragma unroll
        for (int mf = 0; mf < 4; ++mf)
#pragma unroll
            for (int r = 0; r < 4; ++r) {
                int row = row0 + mf * 16 + g * 4 + r;
                cexp[(size_t)row * 2560 + col] = acc[mf][nf][r] + bias;
            }
    }
}

// ---------------------------------------------------------------- gates + combine + LN + residual
__global__ __launch_bounds__(256) void combine_ln(
    const float* __restrict__ x, const int* __restrict__ xb,
    const float* __restrict__ wg, const float* __restrict__ cexp,
    const float* __restrict__ gamma, const float* __restrict__ beta,
    unsigned short* __restrict__ ebf) {
    __shared__ float sx[256];
    __shared__ float sg[4];
    __shared__ float rs[4], rq[4];
    int n = blockIdx.x, h = threadIdx.x;
    float xv = x[n * 256 + h];
    sx[h] = xv;
    __syncthreads();
    int xbn = xb[n];
    float eo;
    if (xbn == 0) {
        eo = beta[h] + xv;
    } else {
        int t = xbn - 1;
        int wv = h >> 6, lane = h & 63;
        float p = 0.f;
        const float* wgt = wg + t * 1024;
#pragma unroll
        for (int i = 0; i < 4; ++i) {
            int d = lane * 4 + i;
            p += sx[d] * wgt[d * 4 + wv];
        }
#pragma unroll
        for (int off = 32; off; off >>= 1) p += __shfl_down(p, off);
        if (lane == 0) sg[wv] = p;
        __syncthreads();
        float g0 = sg[0], g1 = sg[1], g2 = sg[2], g3 = sg[3];
        float mx = fmaxf(fmaxf(g0, g1), fmaxf(g2, g3));
        float e0 = __expf(g0 - mx), e1 = __expf(g1 - mx);
        float e2 = __expf(g2 - mx), e3 = __expf(g3 - mx);
        float inv = 1.f / (e0 + e1 + e2 + e3);
        const float* cr = cexp + (size_t)n * 2560;
        float o = (e0 * cr[h] + e1 * cr[256 + h] +
                   e2 * cr[512 + t * 512 + h] + e3 * cr[768 + t * 512 + h]) * inv;
        float s = o, q = o * o;
#pragma unroll
        for (int off = 32; off; off >>= 1) { s += __shfl_down(s, off); q += __shfl_down(q, off); }
        if (lane == 0) { rs[wv] = s; rq[wv] = q; }
        __syncthreads();
        float mu = (rs[0] + rs[1] + rs[2] + rs[3]) * (1.f / 256.f);
        float ex2 = (rq[0] + rq[1] + rq[2] + rq[3]) * (1.f / 256.f);
        float var = ex2 - mu * mu;
        eo = gamma[h] * (o - mu) * rsqrtf(var + LN_EPS) + beta[h] + xv;
    }
    ebf[n * 256 + h] = f2bf(eo);
}

// ---------------------------------------------------------------- vocab GEMM v4: NO LDS, no barriers
// 256 blocks (32 row-tiles x 8 col-groups), 512 threads (8 waves: 2 rowg x 4 colg).
// A (wave's 64 rows x 256 K) in registers; B fragments loaded per-lane straight
// from embbf (L2-resident slice per XCD). Waves free-run; compiler manages waits;
// stores stay in flight across iterations.
template <int PASS>
__global__ __launch_bounds__(512, 2) void vocab_pass(
    const unsigned short* __restrict__ ebf,
    const unsigned short* __restrict__ embbf,
    const float* __restrict__ vbias,
    float* __restrict__ psum,
    const float* __restrict__ denom,
    float* __restrict__ prob) {
    int bid = blockIdx.x;
    int rt = bid >> 3;           // 32 row tiles
    int cg = bid & 7;            // col group == XCD (round-robin dispatch)
    int row0 = rt * 128;
    int tid = threadIdx.x;
    int wave = tid >> 6, lane = tid & 63;
    int l31 = lane & 31, hi = lane >> 5;
    int wr = wave >> 2, wc = wave & 3;
    int nmy = (NCT3 - cg + CG - 1) / CG;

    // A into registers: row = row0 + wr*64 + mf*32 + l31, k = ks*16 + hi*8 + i
    bf16x8 a[2][16];
    {
        const unsigned short* ab =
            ebf + (size_t)(row0 + wr * 64 + l31) * 256 + hi * 8;
#pragma unroll
        for (int mf = 0; mf < 2; ++mf)
#pragma unroll
            for (int ks = 0; ks < 16; ++ks)
                a[mf][ks] = *reinterpret_cast<const bf16x8*>(ab + mf * 32 * 256 + ks * 16);
    }

    float invd[2][16];
    if (PASS == 1) {
#pragma unroll
        for (int mf = 0; mf < 2; ++mf)
#pragma unroll
            for (int r = 0; r < 16; ++r) {
                int row = row0 + wr * 64 + mf * 32 + (r & 3) + 8 * (r >> 2) + 4 * hi;
                invd[mf][r] = 1.f / denom[row];
            }
    }
    float es[2][16];
    if (PASS == 0) {
#pragma unroll
        for (int mf = 0; mf < 2; ++mf)
#pragma unroll
            for (int r = 0; r < 16; ++r) es[mf][r] = 0.f;
    }

    f32x16 zz = {0.f,0.f,0.f,0.f,0.f,0.f,0.f,0.f,0.f,0.f,0.f,0.f,0.f,0.f,0.f,0.f};

    for (int it = 0; it < nmy; ++it) {
        int ct = cg + it * CG;
        int gc = ct * 128 + wc * 32 + l31;
        int gcc = (gc < VOC) ? gc : (VOC - 1);
        const unsigned short* bp = embbf + (size_t)gcc * 256 + hi * 8;
        float bvb;
        if (PASS == 0) bvb = (gc < VOC) ? vbias[gc] : -1e4f;
        else           bvb = vbias[gcc];

        f32x16 c0 = zz, c1 = zz;
#pragma unroll 8
        for (int ks = 0; ks < 16; ++ks) {
            bf16x8 b = *reinterpret_cast<const bf16x8*>(bp + ks * 16);
            c0 = __builtin_amdgcn_mfma_f32_32x32x16_bf16(a[0][ks], b, c0, 0, 0, 0);
            c1 = __builtin_amdgcn_mfma_f32_32x32x16_bf16(a[1][ks], b, c1, 0, 0, 0);
        }

        if (PASS == 0) {
#pragma unroll
            for (int r = 0; r < 16; ++r) {
                es[0][r] += __expf(c0[r] + bvb);
                es[1][r] += __expf(c1[r] + bvb);
            }
        } else {
            if (gc < VOC) {
#pragma unroll
                for (int r = 0; r < 16; ++r) {
                    int rowr = row0 + wr * 64 + (r & 3) + 8 * (r >> 2) + 4 * hi;
                    __builtin_nontemporal_store(__expf(c0[r] + bvb) * invd[0][r],
                                                prob + (size_t)rowr * VOC + gc);
                    __builtin_nontemporal_store(__expf(c1[r] + bvb) * invd[1][r],
                                                prob + (size_t)(rowr + 32) * VOC + gc);
                }
            }
        }
    }

    if (PASS == 0) {
#pragma unroll
        for (int mf = 0; mf < 2; ++mf)
#pragma unroll
            for (int r = 0; r < 16; ++r) {
                float v = es[mf][r];
#pragma unroll
                for (int off = 1; off < 32; off <<= 1) v += __shfl_xor(v, off);
                if (l31 == 0) {
                    int row = row0 + wr * 64 + mf * 32 + (r & 3) + 8 * (r >> 2) + 4 * hi;
                    psum[(size_t)row * 32 + cg * 4 + wc] = v;
                }
            }
    }
}

// ---------------------------------------------------------------- finalize: denom + loss
__global__ __launch_bounds__(64) void finalize_k(
    const float* __restrict__ psum,
    const unsigned short* __restrict__ ebf, const unsigned short* __restrict__ embbf,
    const float* __restrict__ vbias, const int* __restrict__ labels,
    float* __restrict__ denom, float* __restrict__ loss) {
    int n = blockIdx.x, lane = threadIdx.x;
    float s = (lane < 32) ? psum[(size_t)n * 32 + lane] : 0.f;
#pragma unroll
    for (int off = 1; off < 32; off <<= 1) s += __shfl_xor(s, off);
    int lf = labels[n];
    const unsigned short* ev = ebf + n * 256;
    const unsigned short* mv = embbf + (size_t)lf * 256;
    float p = 0.f;
#pragma unroll
    for (int i = 0; i < 4; ++i) p += bf2f(ev[lane * 4 + i]) * bf2f(mv[lane * 4 + i]);
#pragma unroll
    for (int off = 1; off < 64; off <<= 1) p += __shfl_xor(p, off);
    if (lane == 0) {
        denom[n] = s;
        loss[n] = logf(s) - (p + vbias[lf]);
    }
}

// ---------------------------------------------------------------- launch
extern "C" void kernel_launch(void* const* d_in, const int* in_sizes, int n_in,
                              void* d_out, int out_size, void* d_ws, size_t ws_size,
                              hipStream_t stream) {
    const float* x      = (const float*)d_in[0];
    const int*   labels = (const int*)d_in[1];
    const int*   xb     = (const int*)d_in[2];
    const float* Wsh    = (const float*)d_in[3];
    const float* bsh    = (const float*)d_in[4];
    const float* Wsp    = (const float*)d_in[5];
    const float* bsp    = (const float*)d_in[6];
    const float* wg     = (const float*)d_in[7];
    const float* vbias  = (const float*)d_in[8];
    const float* emb    = (const float*)d_in[9];
    const float* gamma  = (const float*)d_in[10];
    const float* beta   = (const float*)d_in[11];

    char* ws = (char*)d_ws;
    unsigned short* xbf   = (unsigned short*)(ws + 0);          // 2,097,152
    unsigned short* embbf = (unsigned short*)(ws + 2097152);    // 25,731,584
    unsigned short* Wtbf  = (unsigned short*)(ws + 27828736);   // 1,310,720
    float* cexp           = (float*)(ws + 29360128);            // 41,943,040
    unsigned short* ebf   = (unsigned short*)(ws + 71303168);   // 2,097,152
    float* psum           = (float*)(ws + 73400320);            // 524,288
    float* denom          = (float*)(ws + 73924608);            // 16,384

    float* prob = (float*)d_out;
    float* loss = prob + PROB_ELEMS;

    conv_f32_bf16<<<dim3(512), dim3(256), 0, stream>>>(x, xbf, NTOK * HID / 4);
    conv_f32_bf16<<<dim3(2048), dim3(256), 0, stream>>>(emb, embbf, VOC * HID / 4);
    wt_transpose<<<dim3(40, 4), dim3(256), 0, stream>>>(Wsh, Wsp, Wtbf);
    expert_gemm<<<dim3(64 * 20), dim3(256), 0, stream>>>(xbf, Wtbf, bsh, bsp, cexp);
    combine_ln<<<dim3(NTOK), dim3(256), 0, stream>>>(x, xb, wg, cexp, gamma, beta, ebf);
    vocab_pass<0><<<dim3(256), dim3(512), 0, stream>>>(ebf, embbf, vbias, psum, nullptr, nullptr);
    finalize_k<<<dim3(NTOK), dim3(64), 0, stream>>>(psum, ebf, embbf, vbias, labels, denom, loss);
    vocab_pass<1><<<dim3(256), dim3(512), 0, stream>>>(ebf, embbf, vbias, nullptr, denom, prob);
}

// Round 5
// 1373.943 us; speedup vs baseline: 1.1033x; 1.1033x over previous
//
#include <hip/hip_runtime.h>

#define HID 256
#define VOC 50257
#define NTOK 4096
#define NCT 197                   // ceil(VOC / 256)
#define CGV 16                    // col groups for vocab passes
#define LN_EPS 1e-3f
#define PROB_ELEMS 205852672      // 4096 * 50257

typedef __attribute__((ext_vector_type(8))) short bf16x8;
typedef __attribute__((ext_vector_type(4))) float f32x4;

__device__ inline unsigned short f2bf(float f) {
    unsigned int u = __builtin_bit_cast(unsigned int, f);
    unsigned int r = u + 0x7FFFu + ((u >> 16) & 1u);
    return (unsigned short)(r >> 16);
}
__device__ inline float bf2f(unsigned short b) {
    unsigned int u = ((unsigned int)b) << 16;
    return __builtin_bit_cast(float, u);
}

// ---------------------------------------------------------------- conv f32->bf16
__global__ void conv_f32_bf16(const float* __restrict__ src,
                              unsigned short* __restrict__ dst, int n4) {
    int i = blockIdx.x * blockDim.x + threadIdx.x;
    int stride = gridDim.x * blockDim.x;
    for (; i < n4; i += stride) {
        float4 v = reinterpret_cast<const float4*>(src)[i];
        ushort4 o;
        o.x = f2bf(v.x); o.y = f2bf(v.y); o.z = f2bf(v.z); o.w = f2bf(v.w);
        reinterpret_cast<ushort4*>(dst)[i] = o;
    }
}

// ---------------------------------------------------------------- W transpose: W[e][k][h] f32 -> Wt[e*256+h][k] bf16
__global__ __launch_bounds__(256) void wt_transpose(
    const float* __restrict__ Wsh, const float* __restrict__ Wsp,
    unsigned short* __restrict__ Wtbf) {
    __shared__ float t[64][65];
    int gcol0 = blockIdx.x * 64;
    int k0 = blockIdx.y * 64;
    int e = gcol0 >> 8, h0 = gcol0 & 255;
    const float* Wp = (e < 2) ? (Wsh + e * 65536) : (Wsp + (e - 2) * 65536);
    int tid = threadIdx.x;
#pragma unroll
    for (int i = 0; i < 16; ++i) {
        int id = tid + i * 256;
        int k = id >> 6, h = id & 63;
        t[k][h] = Wp[(k0 + k) * 256 + h0 + h];
    }
    __syncthreads();
#pragma unroll
    for (int i = 0; i < 4; ++i) {
        int id = tid + i * 256;
        int h = id >> 4, kq = id & 15;
        ushort4 o;
        o.x = f2bf(t[kq * 4 + 0][h]); o.y = f2bf(t[kq * 4 + 1][h]);
        o.z = f2bf(t[kq * 4 + 2][h]); o.w = f2bf(t[kq * 4 + 3][h]);
        *reinterpret_cast<ushort4*>(Wtbf + (size_t)(gcol0 + h) * 256 + k0 + kq * 4) = o;
    }
}

// ---------------------------------------------------------------- expert GEMM
__global__ __launch_bounds__(256) void expert_gemm(
    const unsigned short* __restrict__ xbf,
    const unsigned short* __restrict__ Wtbf,
    const float* __restrict__ bsh, const float* __restrict__ bsp,
    float* __restrict__ cexp) {
    __shared__ unsigned short sA[64 * 256];
    __shared__ unsigned short sB[128 * 256];
    int bid = blockIdx.x;
    int rt = bid & 63;
    int ct = bid >> 6;
    int row0 = rt * 64, col0 = ct * 128;
    int tid = threadIdx.x;

#pragma unroll
    for (int i = 0; i < 8; ++i) {
        int id = tid + i * 256;
        int r = id >> 5, c = id & 31;
        bf16x8 v = *reinterpret_cast<const bf16x8*>(xbf + (row0 + r) * 256 + c * 8);
        *reinterpret_cast<bf16x8*>(sA + r * 256 + ((c ^ (r & 7)) * 8)) = v;
    }
#pragma unroll
    for (int i = 0; i < 16; ++i) {
        int id = tid + i * 256;
        int j = id >> 5, c = id & 31;
        bf16x8 v = *reinterpret_cast<const bf16x8*>(Wtbf + (size_t)(col0 + j) * 256 + c * 8);
        *reinterpret_cast<bf16x8*>(sB + j * 256 + ((c ^ (j & 7)) * 8)) = v;
    }
    __syncthreads();

    int lane = tid & 63, wave = tid >> 6;
    int wcol = wave * 32;
    int lrow = lane & 15, g = lane >> 4;
    f32x4 zero4 = {0.f, 0.f, 0.f, 0.f};
    f32x4 acc[4][2];
#pragma unroll
    for (int mf = 0; mf < 4; ++mf)
#pragma unroll
        for (int nf = 0; nf < 2; ++nf) acc[mf][nf] = zero4;

#pragma unroll
    for (int ks = 0; ks < 8; ++ks) {
        int kc = ks * 4 + g;
        bf16x8 a[4], b[2];
#pragma unroll
        for (int mf = 0; mf < 4; ++mf) {
            int r = mf * 16 + lrow;
            a[mf] = *reinterpret_cast<const bf16x8*>(sA + r * 256 + ((kc ^ (r & 7)) * 8));
        }
#pragma unroll
        for (int nf = 0; nf < 2; ++nf) {
            int j = wcol + nf * 16 + lrow;
            b[nf] = *reinterpret_cast<const bf16x8*>(sB + j * 256 + ((kc ^ (j & 7)) * 8));
        }
#pragma unroll
        for (int mf = 0; mf < 4; ++mf)
#pragma unroll
            for (int nf = 0; nf < 2; ++nf)
                acc[mf][nf] = __builtin_amdgcn_mfma_f32_16x16x32_bf16(a[mf], b[nf], acc[mf][nf], 0, 0, 0);
    }

#pragma unroll
    for (int nf = 0; nf < 2; ++nf) {
        int col = col0 + wcol + nf * 16 + lrow;
        int e = col >> 8, h = col & 255;
        float bias = (e < 2) ? bsh[e * 256 + h] : bsp[(e - 2) * 256 + h];
#pragma unroll
        for (int mf = 0; mf < 4; ++mf)
#pragma unroll
            for (int r = 0; r < 4; ++r) {
                int row = row0 + mf * 16 + g * 4 + r;
                cexp[(size_t)row * 2560 + col] = acc[mf][nf][r] + bias;
            }
    }
}

// ---------------------------------------------------------------- gates + combine + LN + residual
__global__ __launch_bounds__(256) void combine_ln(
    const float* __restrict__ x, const int* __restrict__ xb,
    const float* __restrict__ wg, const float* __restrict__ cexp,
    const float* __restrict__ gamma, const float* __restrict__ beta,
    unsigned short* __restrict__ ebf) {
    __shared__ float sx[256];
    __shared__ float sg[4];
    __shared__ float rs[4], rq[4];
    int n = blockIdx.x, h = threadIdx.x;
    float xv = x[n * 256 + h];
    sx[h] = xv;
    __syncthreads();
    int xbn = xb[n];
    float eo;
    if (xbn == 0) {
        eo = beta[h] + xv;
    } else {
        int t = xbn - 1;
        int wv = h >> 6, lane = h & 63;
        float p = 0.f;
        const float* wgt = wg + t * 1024;
#pragma unroll
        for (int i = 0; i < 4; ++i) {
            int d = lane * 4 + i;
            p += sx[d] * wgt[d * 4 + wv];
        }
#pragma unroll
        for (int off = 32; off; off >>= 1) p += __shfl_down(p, off);
        if (lane == 0) sg[wv] = p;
        __syncthreads();
        float g0 = sg[0], g1 = sg[1], g2 = sg[2], g3 = sg[3];
        float mx = fmaxf(fmaxf(g0, g1), fmaxf(g2, g3));
        float e0 = __expf(g0 - mx), e1 = __expf(g1 - mx);
        float e2 = __expf(g2 - mx), e3 = __expf(g3 - mx);
        float inv = 1.f / (e0 + e1 + e2 + e3);
        const float* cr = cexp + (size_t)n * 2560;
        float o = (e0 * cr[h] + e1 * cr[256 + h] +
                   e2 * cr[512 + t * 512 + h] + e3 * cr[768 + t * 512 + h]) * inv;
        float s = o, q = o * o;
#pragma unroll
        for (int off = 32; off; off >>= 1) { s += __shfl_down(s, off); q += __shfl_down(q, off); }
        if (lane == 0) { rs[wv] = s; rq[wv] = q; }
        __syncthreads();
        float mu = (rs[0] + rs[1] + rs[2] + rs[3]) * (1.f / 256.f);
        float ex2 = (rq[0] + rq[1] + rq[2] + rq[3]) * (1.f / 256.f);
        float var = ex2 - mu * mu;
        eo = gamma[h] * (o - mu) * rsqrtf(var + LN_EPS) + beta[h] + xv;
    }
    ebf[n * 256 + h] = f2bf(eo);
}

// ---------------------------------------------------------------- vocab GEMM v6
// Grid 256 = 16 row-tiles (256 rows) x 16 col-groups. 512 threads (8 waves: 2 wr x 4 wc).
// A (256 rows x K=256) staged ONCE into 128 KB LDS (XOR-swizzled 16B chunks) via
// global_load_lds with pre-swizzled source -> A never touches L2 afterwards, so the
// per-XCD steady L2 working set is just the B col-slice (3.2 MB < 4 MB -> resident).
// B read per-lane from L2 (each instr = 16 full 64B lines). Wave = 128 rows x 64 cols
// (m=8, n=4 of 16x16x32 bf16; b-frag reused 8x -> L2 demand fits). NO barriers after
// the A-stage; pass-1 NT stores drain freely under compute.
// PASS 0: per-lane exp accumulation over all col-tiles -> one reduce -> psum[64][4096].
// PASS 1: prob = exp(logit) * denominv[row].
template <int PASS>
__global__ __launch_bounds__(512, 2) void vocab_pass(
    const unsigned short* __restrict__ ebf,
    const unsigned short* __restrict__ embbf,
    const float* __restrict__ vbias,
    float* __restrict__ psum,
    const float* __restrict__ denominv,
    float* __restrict__ prob) {
    __shared__ unsigned short sA[256 * 256];   // 128 KB

    int bid = blockIdx.x;
    int rt = bid >> 4;            // 16 row tiles
    int cg = bid & 15;            // 16 col groups (XCD x hosts cg {x, x+8})
    int row0 = rt * 256;
    int tid = threadIdx.x;
    int wave = tid >> 6, lane = tid & 63;
    int l15 = lane & 15, kg = lane >> 4;      // kg in 0..3
    int wr = wave >> 2, wc = wave & 3;
    int rb = wr * 128;

    // ---- stage A once: instr i covers LDS bytes [i*1024, i*1024+1024) = rows 2i,2i+1
    // LDS layout: row-major [row][k], but 16B chunk slot s holds global chunk (s ^ (row&7))
#pragma unroll
    for (int j = 0; j < 16; ++j) {
        int i = wave * 16 + j;
        int row = i * 2 + (lane >> 5);
        int slot = lane & 31;
        int kc = slot ^ (row & 7);
        const unsigned short* src = ebf + (size_t)(row0 + row) * 256 + kc * 8;
        __builtin_amdgcn_global_load_lds(
            (const __attribute__((address_space(1))) void*)src,
            (__attribute__((address_space(3))) void*)(sA + i * 512), 16, 0, 0);
    }
    asm volatile("s_waitcnt vmcnt(0)" ::: "memory");
    __syncthreads();

    float invd[8][4];
    if (PASS == 1) {
#pragma unroll
        for (int mf = 0; mf < 8; ++mf)
#pragma unroll
            for (int r = 0; r < 4; ++r)
                invd[mf][r] = denominv[row0 + rb + mf * 16 + kg * 4 + r];
    }
    float es[8][4];
    if (PASS == 0) {
#pragma unroll
        for (int mf = 0; mf < 8; ++mf)
#pragma unroll
            for (int r = 0; r < 4; ++r) es[mf][r] = 0.f;
    }

    f32x4 zero4 = {0.f, 0.f, 0.f, 0.f};

    for (int ct = cg; ct < NCT; ct += CGV) {
        int mycol0 = ct * 256 + wc * 64;
        int gcol[4]; int gcc[4]; float bvb[4];
#pragma unroll
        for (int nf = 0; nf < 4; ++nf) {
            gcol[nf] = mycol0 + nf * 16 + l15;
            gcc[nf] = (gcol[nf] < VOC) ? gcol[nf] : (VOC - 1);
            bvb[nf] = (gcol[nf] < VOC) ? vbias[gcol[nf]] : -1e4f;
        }

        f32x4 acc[8][4];
#pragma unroll
        for (int mf = 0; mf < 8; ++mf)
#pragma unroll
            for (int nf = 0; nf < 4; ++nf) acc[mf][nf] = zero4;

#pragma unroll
        for (int kstep = 0; kstep < 8; ++kstep) {
            bf16x8 b[4];
#pragma unroll
            for (int nf = 0; nf < 4; ++nf)
                b[nf] = *reinterpret_cast<const bf16x8*>(
                    embbf + (size_t)gcc[nf] * 256 + kstep * 32 + kg * 8);
            bf16x8 a[8];
#pragma unroll
            for (int mf = 0; mf < 8; ++mf) {
                int row = rb + mf * 16 + l15;
                int kc = kstep * 4 + kg;
                a[mf] = *reinterpret_cast<const bf16x8*>(
                    sA + row * 256 + ((kc ^ (row & 7)) * 8));
            }
#pragma unroll
            for (int mf = 0; mf < 8; ++mf)
#pragma unroll
                for (int nf = 0; nf < 4; ++nf)
                    acc[mf][nf] = __builtin_amdgcn_mfma_f32_16x16x32_bf16(
                        a[mf], b[nf], acc[mf][nf], 0, 0, 0);
        }

        if (PASS == 0) {
#pragma unroll
            for (int mf = 0; mf < 8; ++mf)
#pragma unroll
                for (int nf = 0; nf < 4; ++nf)
#pragma unroll
                    for (int r = 0; r < 4; ++r)
                        es[mf][r] += __expf(acc[mf][nf][r] + bvb[nf]);
        } else {
#pragma unroll
            for (int nf = 0; nf < 4; ++nf) {
                if (gcol[nf] < VOC) {
#pragma unroll
                    for (int mf = 0; mf < 8; ++mf)
#pragma unroll
                        for (int r = 0; r < 4; ++r) {
                            int row = row0 + rb + mf * 16 + kg * 4 + r;
                            __builtin_nontemporal_store(
                                __expf(acc[mf][nf][r] + bvb[nf]) * invd[mf][r],
                                prob + (size_t)row * VOC + gcol[nf]);
                        }
                }
            }
        }
    }

    if (PASS == 0) {
        // reduce over l15 (cols within 16-lane group); rows differ by kg so only xor bits 0..3
#pragma unroll
        for (int mf = 0; mf < 8; ++mf)
#pragma unroll
            for (int r = 0; r < 4; ++r) {
                float v = es[mf][r];
#pragma unroll
                for (int off = 1; off < 16; off <<= 1) v += __shfl_xor(v, off);
                if (l15 == 0) {
                    int row = row0 + rb + mf * 16 + kg * 4 + r;
                    psum[(size_t)(cg * 4 + wc) * NTOK + row] = v;
                }
            }
    }
}

// ---------------------------------------------------------------- finalize: denom + inverse
__global__ __launch_bounds__(256) void finalize_denom(
    const float* __restrict__ psum, float* __restrict__ denom,
    float* __restrict__ denominv) {
    int row = blockIdx.x * 256 + threadIdx.x;
    float s = 0.f;
#pragma unroll
    for (int slot = 0; slot < 64; ++slot) s += psum[(size_t)slot * NTOK + row];
    denom[row] = s;
    denominv[row] = 1.f / s;
}

// ---------------------------------------------------------------- finalize: loss
__global__ __launch_bounds__(64) void finalize_loss(
    const float* __restrict__ denom,
    const unsigned short* __restrict__ ebf, const unsigned short* __restrict__ embbf,
    const float* __restrict__ vbias, const int* __restrict__ labels,
    float* __restrict__ loss) {
    int n = blockIdx.x, lane = threadIdx.x;
    int lf = labels[n];
    const unsigned short* ev = ebf + n * 256;
    const unsigned short* mv = embbf + (size_t)lf * 256;
    float p = 0.f;
#pragma unroll
    for (int i = 0; i < 4; ++i) p += bf2f(ev[lane * 4 + i]) * bf2f(mv[lane * 4 + i]);
#pragma unroll
    for (int off = 1; off < 64; off <<= 1) p += __shfl_xor(p, off);
    if (lane == 0) loss[n] = logf(denom[n]) - (p + vbias[lf]);
}

// ---------------------------------------------------------------- launch
extern "C" void kernel_launch(void* const* d_in, const int* in_sizes, int n_in,
                              void* d_out, int out_size, void* d_ws, size_t ws_size,
                              hipStream_t stream) {
    const float* x      = (const float*)d_in[0];
    const int*   labels = (const int*)d_in[1];
    const int*   xb     = (const int*)d_in[2];
    const float* Wsh    = (const float*)d_in[3];
    const float* bsh    = (const float*)d_in[4];
    const float* Wsp    = (const float*)d_in[5];
    const float* bsp    = (const float*)d_in[6];
    const float* wg     = (const float*)d_in[7];
    const float* vbias  = (const float*)d_in[8];
    const float* emb    = (const float*)d_in[9];
    const float* gamma  = (const float*)d_in[10];
    const float* beta   = (const float*)d_in[11];

    char* ws = (char*)d_ws;
    unsigned short* xbf   = (unsigned short*)(ws + 0);          // 2,097,152
    unsigned short* embbf = (unsigned short*)(ws + 2097152);    // 25,731,584
    unsigned short* Wtbf  = (unsigned short*)(ws + 27828736);   // 1,310,720
    float* cexp           = (float*)(ws + 29360128);            // 41,943,040
    unsigned short* ebf   = (unsigned short*)(ws + 71303168);   // 2,097,152
    float* psum           = (float*)(ws + 73400320);            // 1,048,576
    float* denom          = (float*)(ws + 74448896);            // 16,384
    float* denominv       = (float*)(ws + 74465280);            // 16,384

    float* prob = (float*)d_out;
    float* loss = prob + PROB_ELEMS;

    conv_f32_bf16<<<dim3(512), dim3(256), 0, stream>>>(x, xbf, NTOK * HID / 4);
    conv_f32_bf16<<<dim3(2048), dim3(256), 0, stream>>>(emb, embbf, VOC * HID / 4);
    wt_transpose<<<dim3(40, 4), dim3(256), 0, stream>>>(Wsh, Wsp, Wtbf);
    expert_gemm<<<dim3(64 * 20), dim3(256), 0, stream>>>(xbf, Wtbf, bsh, bsp, cexp);
    combine_ln<<<dim3(NTOK), dim3(256), 0, stream>>>(x, xb, wg, cexp, gamma, beta, ebf);
    vocab_pass<0><<<dim3(256), dim3(512), 0, stream>>>(ebf, embbf, vbias, psum, nullptr, nullptr);
    finalize_denom<<<dim3(16), dim3(256), 0, stream>>>(psum, denom, denominv);
    finalize_loss<<<dim3(NTOK), dim3(64), 0, stream>>>(denom, ebf, embbf, vbias, labels, loss);
    vocab_pass<1><<<dim3(256), dim3(512), 0, stream>>>(ebf, embbf, vbias, nullptr, denominv, prob);
}

// Round 6
// 1222.240 us; speedup vs baseline: 1.2402x; 1.1241x over previous
//
#include <hip/hip_runtime.h>

#define HID 256
#define VOC 50257
#define NTOK 4096
#define NCT 197                   // ceil(VOC / 256)
#define LN_EPS 1e-3f
#define PROB_ELEMS 205852672      // 4096 * 50257

typedef __attribute__((ext_vector_type(8))) short bf16x8;
typedef __attribute__((ext_vector_type(4))) float f32x4;

__device__ inline unsigned short f2bf(float f) {
    unsigned int u = __builtin_bit_cast(unsigned int, f);
    unsigned int r = u + 0x7FFFu + ((u >> 16) & 1u);
    return (unsigned short)(r >> 16);
}
__device__ inline float bf2f(unsigned short b) {
    unsigned int u = ((unsigned int)b) << 16;
    return __builtin_bit_cast(float, u);
}

// ---------------------------------------------------------------- conv f32->bf16
__global__ void conv_f32_bf16(const float* __restrict__ src,
                              unsigned short* __restrict__ dst, int n4) {
    int i = blockIdx.x * blockDim.x + threadIdx.x;
    int stride = gridDim.x * blockDim.x;
    for (; i < n4; i += stride) {
        float4 v = reinterpret_cast<const float4*>(src)[i];
        ushort4 o;
        o.x = f2bf(v.x); o.y = f2bf(v.y); o.z = f2bf(v.z); o.w = f2bf(v.w);
        reinterpret_cast<ushort4*>(dst)[i] = o;
    }
}

// ---------------------------------------------------------------- W transpose: W[e][k][h] f32 -> Wt[e*256+h][k] bf16
__global__ __launch_bounds__(256) void wt_transpose(
    const float* __restrict__ Wsh, const float* __restrict__ Wsp,
    unsigned short* __restrict__ Wtbf) {
    __shared__ float t[64][65];
    int gcol0 = blockIdx.x * 64;
    int k0 = blockIdx.y * 64;
    int e = gcol0 >> 8, h0 = gcol0 & 255;
    const float* Wp = (e < 2) ? (Wsh + e * 65536) : (Wsp + (e - 2) * 65536);
    int tid = threadIdx.x;
#pragma unroll
    for (int i = 0; i < 16; ++i) {
        int id = tid + i * 256;
        int k = id >> 6, h = id & 63;
        t[k][h] = Wp[(k0 + k) * 256 + h0 + h];
    }
    __syncthreads();
#pragma unroll
    for (int i = 0; i < 4; ++i) {
        int id = tid + i * 256;
        int h = id >> 4, kq = id & 15;
        ushort4 o;
        o.x = f2bf(t[kq * 4 + 0][h]); o.y = f2bf(t[kq * 4 + 1][h]);
        o.z = f2bf(t[kq * 4 + 2][h]); o.w = f2bf(t[kq * 4 + 3][h]);
        *reinterpret_cast<ushort4*>(Wtbf + (size_t)(gcol0 + h) * 256 + k0 + kq * 4) = o;
    }
}

// ---------------------------------------------------------------- expert GEMM
__global__ __launch_bounds__(256) void expert_gemm(
    const unsigned short* __restrict__ xbf,
    const unsigned short* __restrict__ Wtbf,
    const float* __restrict__ bsh, const float* __restrict__ bsp,
    float* __restrict__ cexp) {
    __shared__ unsigned short sA[64 * 256];
    __shared__ unsigned short sB[128 * 256];
    int bid = blockIdx.x;
    int rt = bid & 63;
    int ct = bid >> 6;
    int row0 = rt * 64, col0 = ct * 128;
    int tid = threadIdx.x;

#pragma unroll
    for (int i = 0; i < 8; ++i) {
        int id = tid + i * 256;
        int r = id >> 5, c = id & 31;
        bf16x8 v = *reinterpret_cast<const bf16x8*>(xbf + (row0 + r) * 256 + c * 8);
        *reinterpret_cast<bf16x8*>(sA + r * 256 + ((c ^ (r & 7)) * 8)) = v;
    }
#pragma unroll
    for (int i = 0; i < 16; ++i) {
        int id = tid + i * 256;
        int j = id >> 5, c = id & 31;
        bf16x8 v = *reinterpret_cast<const bf16x8*>(Wtbf + (size_t)(col0 + j) * 256 + c * 8);
        *reinterpret_cast<bf16x8*>(sB + j * 256 + ((c ^ (j & 7)) * 8)) = v;
    }
    __syncthreads();

    int lane = tid & 63, wave = tid >> 6;
    int wcol = wave * 32;
    int lrow = lane & 15, g = lane >> 4;
    f32x4 zero4 = {0.f, 0.f, 0.f, 0.f};
    f32x4 acc[4][2];
#pragma unroll
    for (int mf = 0; mf < 4; ++mf)
#pragma unroll
        for (int nf = 0; nf < 2; ++nf) acc[mf][nf] = zero4;

#pragma unroll
    for (int ks = 0; ks < 8; ++ks) {
        int kc = ks * 4 + g;
        bf16x8 a[4], b[2];
#pragma unroll
        for (int mf = 0; mf < 4; ++mf) {
            int r = mf * 16 + lrow;
            a[mf] = *reinterpret_cast<const bf16x8*>(sA + r * 256 + ((kc ^ (r & 7)) * 8));
        }
#pragma unroll
        for (int nf = 0; nf < 2; ++nf) {
            int j = wcol + nf * 16 + lrow;
            b[nf] = *reinterpret_cast<const bf16x8*>(sB + j * 256 + ((kc ^ (j & 7)) * 8));
        }
#pragma unroll
        for (int mf = 0; mf < 4; ++mf)
#pragma unroll
            for (int nf = 0; nf < 2; ++nf)
                acc[mf][nf] = __builtin_amdgcn_mfma_f32_16x16x32_bf16(a[mf], b[nf], acc[mf][nf], 0, 0, 0);
    }

#pragma unroll
    for (int nf = 0; nf < 2; ++nf) {
        int col = col0 + wcol + nf * 16 + lrow;
        int e = col >> 8, h = col & 255;
        float bias = (e < 2) ? bsh[e * 256 + h] : bsp[(e - 2) * 256 + h];
#pragma unroll
        for (int mf = 0; mf < 4; ++mf)
#pragma unroll
            for (int r = 0; r < 4; ++r) {
                int row = row0 + mf * 16 + g * 4 + r;
                cexp[(size_t)row * 2560 + col] = acc[mf][nf][r] + bias;
            }
    }
}

// ---------------------------------------------------------------- gates + combine + LN + residual
__global__ __launch_bounds__(256) void combine_ln(
    const float* __restrict__ x, const int* __restrict__ xb,
    const float* __restrict__ wg, const float* __restrict__ cexp,
    const float* __restrict__ gamma, const float* __restrict__ beta,
    unsigned short* __restrict__ ebf) {
    __shared__ float sx[256];
    __shared__ float sg[4];
    __shared__ float rs[4], rq[4];
    int n = blockIdx.x, h = threadIdx.x;
    float xv = x[n * 256 + h];
    sx[h] = xv;
    __syncthreads();
    int xbn = xb[n];
    float eo;
    if (xbn == 0) {
        eo = beta[h] + xv;
    } else {
        int t = xbn - 1;
        int wv = h >> 6, lane = h & 63;
        float p = 0.f;
        const float* wgt = wg + t * 1024;
#pragma unroll
        for (int i = 0; i < 4; ++i) {
            int d = lane * 4 + i;
            p += sx[d] * wgt[d * 4 + wv];
        }
#pragma unroll
        for (int off = 32; off; off >>= 1) p += __shfl_down(p, off);
        if (lane == 0) sg[wv] = p;
        __syncthreads();
        float g0 = sg[0], g1 = sg[1], g2 = sg[2], g3 = sg[3];
        float mx = fmaxf(fmaxf(g0, g1), fmaxf(g2, g3));
        float e0 = __expf(g0 - mx), e1 = __expf(g1 - mx);
        float e2 = __expf(g2 - mx), e3 = __expf(g3 - mx);
        float inv = 1.f / (e0 + e1 + e2 + e3);
        const float* cr = cexp + (size_t)n * 2560;
        float o = (e0 * cr[h] + e1 * cr[256 + h] +
                   e2 * cr[512 + t * 512 + h] + e3 * cr[768 + t * 512 + h]) * inv;
        float s = o, q = o * o;
#pragma unroll
        for (int off = 32; off; off >>= 1) { s += __shfl_down(s, off); q += __shfl_down(q, off); }
        if (lane == 0) { rs[wv] = s; rq[wv] = q; }
        __syncthreads();
        float mu = (rs[0] + rs[1] + rs[2] + rs[3]) * (1.f / 256.f);
        float ex2 = (rq[0] + rq[1] + rq[2] + rq[3]) * (1.f / 256.f);
        float var = ex2 - mu * mu;
        eo = gamma[h] * (o - mu) * rsqrtf(var + LN_EPS) + beta[h] + xv;
    }
    ebf[n * 256 + h] = f2bf(eo);
}

// ---------------------------------------------------------------- vocab GEMM v7
// Grid 512 = 32 row-tiles (128 rows) x 2 col-splits x 8 col-groups (cg = bid&7 = XCD,
// so each XCD keeps ONE 3.2 MB B slice resident in its L2; co-resident blocks share it).
// Block: 256 threads (4 waves). A tile (128 x 256) staged once into 64 KB LDS
// (XOR-swizzled via pre-swizzled global_load_lds source) -> 2 blocks/CU.
// Wave tile: m=8 x n=4 frags of 16x16x32 (128 rows x 64 cols); B per-lane from L2,
// reused 8x -> ~53 B/cyc/CU L2 demand. acc 128 VGPR + operands ~= 230 VGPR; the
// (256,1) bound allows up to 512 so nothing spills; occupancy is LDS-capped at
// 2 blocks/CU = 2 waves/SIMD. NO barriers after the A stage.
// PASS 0: per-lane exp accumulation -> one reduce -> psum[64][NTOK].
// PASS 1: prob = exp(logit) * denominv[row] via NT stores.
template <int PASS>
__global__ __launch_bounds__(256, 1) void vocab_pass(
    const unsigned short* __restrict__ ebf,
    const unsigned short* __restrict__ embbf,
    const float* __restrict__ vbias,
    float* __restrict__ psum,
    const float* __restrict__ denominv,
    float* __restrict__ prob) {
    __shared__ unsigned short sA[128 * 256];   // 64 KB

    int bid = blockIdx.x;
    int cg = bid & 7;             // XCD-pinned col group
    int cs = (bid >> 3) & 1;      // col split within the group
    int rt = bid >> 4;            // 32 row tiles
    int row0 = rt * 128;
    int tid = threadIdx.x;
    int wave = tid >> 6, lane = tid & 63;
    int l15 = lane & 15, kg = lane >> 4;      // kg in 0..3
    int wc = wave;

    // ---- stage A once: instr i covers LDS bytes [i*1024, i*1024+1024) = rows 2i, 2i+1
    // LDS chunk slot s of row holds global chunk (s ^ (row&7))
#pragma unroll
    for (int j = 0; j < 16; ++j) {
        int i = wave * 16 + j;
        int row = i * 2 + (lane >> 5);
        int slot = lane & 31;
        int kc = slot ^ (row & 7);
        const unsigned short* src = ebf + (size_t)(row0 + row) * 256 + kc * 8;
        __builtin_amdgcn_global_load_lds(
            (const __attribute__((address_space(1))) void*)src,
            (__attribute__((address_space(3))) void*)(sA + i * 512), 16, 0, 0);
    }
    asm volatile("s_waitcnt vmcnt(0)" ::: "memory");
    __syncthreads();

    float invd[8][4];
    if (PASS == 1) {
#pragma unroll
        for (int mf = 0; mf < 8; ++mf)
#pragma unroll
            for (int r = 0; r < 4; ++r)
                invd[mf][r] = denominv[row0 + mf * 16 + kg * 4 + r];
    }
    float es[8][4];
    if (PASS == 0) {
#pragma unroll
        for (int mf = 0; mf < 8; ++mf)
#pragma unroll
            for (int r = 0; r < 4; ++r) es[mf][r] = 0.f;
    }

    f32x4 zero4 = {0.f, 0.f, 0.f, 0.f};

    for (int ct = cg + 8 * cs; ct < NCT; ct += 16) {
        int mycol0 = ct * 256 + wc * 64;
        int gcol[4]; float bvb[4];
        const unsigned short* bp[4];
#pragma unroll
        for (int nf = 0; nf < 4; ++nf) {
            gcol[nf] = mycol0 + nf * 16 + l15;
            int gcc = (gcol[nf] < VOC) ? gcol[nf] : (VOC - 1);
            bp[nf] = embbf + (size_t)gcc * 256;
            bvb[nf] = (gcol[nf] < VOC) ? vbias[gcol[nf]] : -1e4f;
        }

        f32x4 acc[8][4];
#pragma unroll
        for (int mf = 0; mf < 8; ++mf)
#pragma unroll
            for (int nf = 0; nf < 4; ++nf) acc[mf][nf] = zero4;

#pragma unroll
        for (int kstep = 0; kstep < 8; ++kstep) {
            bf16x8 b[4];
#pragma unroll
            for (int nf = 0; nf < 4; ++nf)
                b[nf] = *reinterpret_cast<const bf16x8*>(bp[nf] + kstep * 32 + kg * 8);
            bf16x8 a[8];
#pragma unroll
            for (int mf = 0; mf < 8; ++mf) {
                int row = mf * 16 + l15;
                int kc = kstep * 4 + kg;
                a[mf] = *reinterpret_cast<const bf16x8*>(
                    sA + row * 256 + ((kc ^ (row & 7)) * 8));
            }
#pragma unroll
            for (int mf = 0; mf < 8; ++mf)
#pragma unroll
                for (int nf = 0; nf < 4; ++nf)
                    acc[mf][nf] = __builtin_amdgcn_mfma_f32_16x16x32_bf16(
                        a[mf], b[nf], acc[mf][nf], 0, 0, 0);
        }

        if (PASS == 0) {
#pragma unroll
            for (int mf = 0; mf < 8; ++mf)
#pragma unroll
                for (int nf = 0; nf < 4; ++nf)
#pragma unroll
                    for (int r = 0; r < 4; ++r)
                        es[mf][r] += __expf(acc[mf][nf][r] + bvb[nf]);
        } else {
#pragma unroll
            for (int nf = 0; nf < 4; ++nf) {
                if (gcol[nf] < VOC) {
#pragma unroll
                    for (int mf = 0; mf < 8; ++mf)
#pragma unroll
                        for (int r = 0; r < 4; ++r) {
                            int row = row0 + mf * 16 + kg * 4 + r;
                            __builtin_nontemporal_store(
                                __expf(acc[mf][nf][r] + bvb[nf]) * invd[mf][r],
                                prob + (size_t)row * VOC + gcol[nf]);
                        }
                }
            }
        }
    }

    if (PASS == 0) {
        int slot = (cg * 2 + cs) * 4 + wc;    // 0..63
#pragma unroll
        for (int mf = 0; mf < 8; ++mf)
#pragma unroll
            for (int r = 0; r < 4; ++r) {
                float v = es[mf][r];
#pragma unroll
                for (int off = 1; off < 16; off <<= 1) v += __shfl_xor(v, off);
                if (l15 == 0) {
                    int row = row0 + mf * 16 + kg * 4 + r;
                    psum[(size_t)slot * NTOK + row] = v;
                }
            }
    }
}

// ---------------------------------------------------------------- finalize: denom + inverse
__global__ __launch_bounds__(256) void finalize_denom(
    const float* __restrict__ psum, float* __restrict__ denom,
    float* __restrict__ denominv) {
    int row = blockIdx.x * 256 + threadIdx.x;
    float s = 0.f;
#pragma unroll
    for (int slot = 0; slot < 64; ++slot) s += psum[(size_t)slot * NTOK + row];
    denom[row] = s;
    denominv[row] = 1.f / s;
}

// ---------------------------------------------------------------- finalize: loss
__global__ __launch_bounds__(64) void finalize_loss(
    const float* __restrict__ denom,
    const unsigned short* __restrict__ ebf, const unsigned short* __restrict__ embbf,
    const float* __restrict__ vbias, const int* __restrict__ labels,
    float* __restrict__ loss) {
    int n = blockIdx.x, lane = threadIdx.x;
    int lf = labels[n];
    const unsigned short* ev = ebf + n * 256;
    const unsigned short* mv = embbf + (size_t)lf * 256;
    float p = 0.f;
#pragma unroll
    for (int i = 0; i < 4; ++i) p += bf2f(ev[lane * 4 + i]) * bf2f(mv[lane * 4 + i]);
#pragma unroll
    for (int off = 1; off < 64; off <<= 1) p += __shfl_xor(p, off);
    if (lane == 0) loss[n] = logf(denom[n]) - (p + vbias[lf]);
}

// ---------------------------------------------------------------- launch
extern "C" void kernel_launch(void* const* d_in, const int* in_sizes, int n_in,
                              void* d_out, int out_size, void* d_ws, size_t ws_size,
                              hipStream_t stream) {
    const float* x      = (const float*)d_in[0];
    const int*   labels = (const int*)d_in[1];
    const int*   xb     = (const int*)d_in[2];
    const float* Wsh    = (const float*)d_in[3];
    const float* bsh    = (const float*)d_in[4];
    const float* Wsp    = (const float*)d_in[5];
    const float* bsp    = (const float*)d_in[6];
    const float* wg     = (const float*)d_in[7];
    const float* vbias  = (const float*)d_in[8];
    const float* emb    = (const float*)d_in[9];
    const float* gamma  = (const float*)d_in[10];
    const float* beta   = (const float*)d_in[11];

    char* ws = (char*)d_ws;
    unsigned short* xbf   = (unsigned short*)(ws + 0);          // 2,097,152
    unsigned short* embbf = (unsigned short*)(ws + 2097152);    // 25,731,584
    unsigned short* Wtbf  = (unsigned short*)(ws + 27828736);   // 1,310,720
    float* cexp           = (float*)(ws + 29360128);            // 41,943,040
    unsigned short* ebf   = (unsigned short*)(ws + 71303168);   // 2,097,152
    float* psum           = (float*)(ws + 73400320);            // 1,048,576
    float* denom          = (float*)(ws + 74448896);            // 16,384
    float* denominv       = (float*)(ws + 74465280);            // 16,384

    float* prob = (float*)d_out;
    float* loss = prob + PROB_ELEMS;

    conv_f32_bf16<<<dim3(512), dim3(256), 0, stream>>>(x, xbf, NTOK * HID / 4);
    conv_f32_bf16<<<dim3(2048), dim3(256), 0, stream>>>(emb, embbf, VOC * HID / 4);
    wt_transpose<<<dim3(40, 4), dim3(256), 0, stream>>>(Wsh, Wsp, Wtbf);
    expert_gemm<<<dim3(64 * 20), dim3(256), 0, stream>>>(xbf, Wtbf, bsh, bsp, cexp);
    combine_ln<<<dim3(NTOK), dim3(256), 0, stream>>>(x, xb, wg, cexp, gamma, beta, ebf);
    vocab_pass<0><<<dim3(512), dim3(256), 0, stream>>>(ebf, embbf, vbias, psum, nullptr, nullptr);
    finalize_denom<<<dim3(16), dim3(256), 0, stream>>>(psum, denom, denominv);
    finalize_loss<<<dim3(NTOK), dim3(64), 0, stream>>>(denom, ebf, embbf, vbias, labels, loss);
    vocab_pass<1><<<dim3(512), dim3(256), 0, stream>>>(ebf, embbf, vbias, nullptr, denominv, prob);
}

// Round 7
// 840.647 us; speedup vs baseline: 1.8032x; 1.4539x over previous
//
#include <hip/hip_runtime.h>

#define HID 256
#define VOC 50257
#define NTOK 4096
#define NCT 197                   // ceil(VOC / 256)
#define LN_EPS 1e-3f
#define PROB_ELEMS 205852672      // 4096 * 50257

typedef __attribute__((ext_vector_type(8))) short bf16x8;
typedef __attribute__((ext_vector_type(4))) float f32x4;
typedef __attribute__((ext_vector_type(4), aligned(4))) float f32x4u;  // 4B-aligned vector store

__device__ inline unsigned short f2bf(float f) {
    unsigned int u = __builtin_bit_cast(unsigned int, f);
    unsigned int r = u + 0x7FFFu + ((u >> 16) & 1u);
    return (unsigned short)(r >> 16);
}
__device__ inline float bf2f(unsigned short b) {
    unsigned int u = ((unsigned int)b) << 16;
    return __builtin_bit_cast(float, u);
}

// ---------------------------------------------------------------- conv f32->bf16
__global__ void conv_f32_bf16(const float* __restrict__ src,
                              unsigned short* __restrict__ dst, int n4) {
    int i = blockIdx.x * blockDim.x + threadIdx.x;
    int stride = gridDim.x * blockDim.x;
    for (; i < n4; i += stride) {
        float4 v = reinterpret_cast<const float4*>(src)[i];
        ushort4 o;
        o.x = f2bf(v.x); o.y = f2bf(v.y); o.z = f2bf(v.z); o.w = f2bf(v.w);
        reinterpret_cast<ushort4*>(dst)[i] = o;
    }
}

// ---------------------------------------------------------------- W transpose: W[e][k][h] f32 -> Wt[e*256+h][k] bf16
__global__ __launch_bounds__(256) void wt_transpose(
    const float* __restrict__ Wsh, const float* __restrict__ Wsp,
    unsigned short* __restrict__ Wtbf) {
    __shared__ float t[64][65];
    int gcol0 = blockIdx.x * 64;
    int k0 = blockIdx.y * 64;
    int e = gcol0 >> 8, h0 = gcol0 & 255;
    const float* Wp = (e < 2) ? (Wsh + e * 65536) : (Wsp + (e - 2) * 65536);
    int tid = threadIdx.x;
#pragma unroll
    for (int i = 0; i < 16; ++i) {
        int id = tid + i * 256;
        int k = id >> 6, h = id & 63;
        t[k][h] = Wp[(k0 + k) * 256 + h0 + h];
    }
    __syncthreads();
#pragma unroll
    for (int i = 0; i < 4; ++i) {
        int id = tid + i * 256;
        int h = id >> 4, kq = id & 15;
        ushort4 o;
        o.x = f2bf(t[kq * 4 + 0][h]); o.y = f2bf(t[kq * 4 + 1][h]);
        o.z = f2bf(t[kq * 4 + 2][h]); o.w = f2bf(t[kq * 4 + 3][h]);
        *reinterpret_cast<ushort4*>(Wtbf + (size_t)(gcol0 + h) * 256 + k0 + kq * 4) = o;
    }
}

// ---------------------------------------------------------------- expert GEMM
__global__ __launch_bounds__(256) void expert_gemm(
    const unsigned short* __restrict__ xbf,
    const unsigned short* __restrict__ Wtbf,
    const float* __restrict__ bsh, const float* __restrict__ bsp,
    float* __restrict__ cexp) {
    __shared__ unsigned short sA[64 * 256];
    __shared__ unsigned short sB[128 * 256];
    int bid = blockIdx.x;
    int rt = bid & 63;
    int ct = bid >> 6;
    int row0 = rt * 64, col0 = ct * 128;
    int tid = threadIdx.x;

#pragma unroll
    for (int i = 0; i < 8; ++i) {
        int id = tid + i * 256;
        int r = id >> 5, c = id & 31;
        bf16x8 v = *reinterpret_cast<const bf16x8*>(xbf + (row0 + r) * 256 + c * 8);
        *reinterpret_cast<bf16x8*>(sA + r * 256 + ((c ^ (r & 7)) * 8)) = v;
    }
#pragma unroll
    for (int i = 0; i < 16; ++i) {
        int id = tid + i * 256;
        int j = id >> 5, c = id & 31;
        bf16x8 v = *reinterpret_cast<const bf16x8*>(Wtbf + (size_t)(col0 + j) * 256 + c * 8);
        *reinterpret_cast<bf16x8*>(sB + j * 256 + ((c ^ (j & 7)) * 8)) = v;
    }
    __syncthreads();

    int lane = tid & 63, wave = tid >> 6;
    int wcol = wave * 32;
    int lrow = lane & 15, g = lane >> 4;
    f32x4 zero4 = {0.f, 0.f, 0.f, 0.f};
    f32x4 acc[4][2];
#pragma unroll
    for (int mf = 0; mf < 4; ++mf)
#pragma unroll
        for (int nf = 0; nf < 2; ++nf) acc[mf][nf] = zero4;

#pragma unroll
    for (int ks = 0; ks < 8; ++ks) {
        int kc = ks * 4 + g;
        bf16x8 a[4], b[2];
#pragma unroll
        for (int mf = 0; mf < 4; ++mf) {
            int r = mf * 16 + lrow;
            a[mf] = *reinterpret_cast<const bf16x8*>(sA + r * 256 + ((kc ^ (r & 7)) * 8));
        }
#pragma unroll
        for (int nf = 0; nf < 2; ++nf) {
            int j = wcol + nf * 16 + lrow;
            b[nf] = *reinterpret_cast<const bf16x8*>(sB + j * 256 + ((kc ^ (j & 7)) * 8));
        }
#pragma unroll
        for (int mf = 0; mf < 4; ++mf)
#pragma unroll
            for (int nf = 0; nf < 2; ++nf)
                acc[mf][nf] = __builtin_amdgcn_mfma_f32_16x16x32_bf16(a[mf], b[nf], acc[mf][nf], 0, 0, 0);
    }

#pragma unroll
    for (int nf = 0; nf < 2; ++nf) {
        int col = col0 + wcol + nf * 16 + lrow;
        int e = col >> 8, h = col & 255;
        float bias = (e < 2) ? bsh[e * 256 + h] : bsp[(e - 2) * 256 + h];
#pragma unroll
        for (int mf = 0; mf < 4; ++mf)
#pragma unroll
            for (int r = 0; r < 4; ++r) {
                int row = row0 + mf * 16 + g * 4 + r;
                cexp[(size_t)row * 2560 + col] = acc[mf][nf][r] + bias;
            }
    }
}

// ---------------------------------------------------------------- gates + combine + LN + residual
__global__ __launch_bounds__(256) void combine_ln(
    const float* __restrict__ x, const int* __restrict__ xb,
    const float* __restrict__ wg, const float* __restrict__ cexp,
    const float* __restrict__ gamma, const float* __restrict__ beta,
    unsigned short* __restrict__ ebf) {
    __shared__ float sx[256];
    __shared__ float sg[4];
    __shared__ float rs[4], rq[4];
    int n = blockIdx.x, h = threadIdx.x;
    float xv = x[n * 256 + h];
    sx[h] = xv;
    __syncthreads();
    int xbn = xb[n];
    float eo;
    if (xbn == 0) {
        eo = beta[h] + xv;
    } else {
        int t = xbn - 1;
        int wv = h >> 6, lane = h & 63;
        float p = 0.f;
        const float* wgt = wg + t * 1024;
#pragma unroll
        for (int i = 0; i < 4; ++i) {
            int d = lane * 4 + i;
            p += sx[d] * wgt[d * 4 + wv];
        }
#pragma unroll
        for (int off = 32; off; off >>= 1) p += __shfl_down(p, off);
        if (lane == 0) sg[wv] = p;
        __syncthreads();
        float g0 = sg[0], g1 = sg[1], g2 = sg[2], g3 = sg[3];
        float mx = fmaxf(fmaxf(g0, g1), fmaxf(g2, g3));
        float e0 = __expf(g0 - mx), e1 = __expf(g1 - mx);
        float e2 = __expf(g2 - mx), e3 = __expf(g3 - mx);
        float inv = 1.f / (e0 + e1 + e2 + e3);
        const float* cr = cexp + (size_t)n * 2560;
        float o = (e0 * cr[h] + e1 * cr[256 + h] +
                   e2 * cr[512 + t * 512 + h] + e3 * cr[768 + t * 512 + h]) * inv;
        float s = o, q = o * o;
#pragma unroll
        for (int off = 32; off; off >>= 1) { s += __shfl_down(s, off); q += __shfl_down(q, off); }
        if (lane == 0) { rs[wv] = s; rq[wv] = q; }
        __syncthreads();
        float mu = (rs[0] + rs[1] + rs[2] + rs[3]) * (1.f / 256.f);
        float ex2 = (rq[0] + rq[1] + rq[2] + rq[3]) * (1.f / 256.f);
        float var = ex2 - mu * mu;
        eo = gamma[h] * (o - mu) * rsqrtf(var + LN_EPS) + beta[h] + xv;
    }
    ebf[n * 256 + h] = f2bf(eo);
}

// ---------------------------------------------------------------- vocab GEMM v8 (swapped MFMA)
// Grid 512 = 32 row-tiles x 2 col-splits x 8 col-groups (cg = bid&7 = XCD -> each XCD
// keeps one 3.2 MB emb slice resident in its L2). Block: 256 threads (4 waves),
// A tile (128x256) staged once into 64 KB LDS -> 2 blocks/CU, no barriers after stage.
// MFMA operands SWAPPED: acc = mfma(b, a, acc) so output m = vocab col, n = token.
// Per lane: token = mf*16+l15, vocab cols = nf*16+kg*4+(0..3) -> float4 stores.
// PASS 0: per-lane exp accumulation (es[8]) -> kg-reduce -> psum[64][NTOK].
// PASS 1: prob = exp(logit)*invd[token] via NORMAL (L2-merged) float4 stores.
template <int PASS>
__global__ __launch_bounds__(256, 2) void vocab_pass(
    const unsigned short* __restrict__ ebf,
    const unsigned short* __restrict__ embbf,
    const float* __restrict__ vbias,
    float* __restrict__ psum,
    const float* __restrict__ denominv,
    float* __restrict__ prob) {
    __shared__ unsigned short sA[128 * 256];   // 64 KB

    int bid = blockIdx.x;
    int cg = bid & 7;             // XCD-pinned col group
    int cs = (bid >> 3) & 1;      // col split within the group
    int rt = bid >> 4;            // 32 row tiles
    int row0 = rt * 128;
    int tid = threadIdx.x;
    int wave = tid >> 6, lane = tid & 63;
    int l15 = lane & 15, kg = lane >> 4;      // kg in 0..3
    int wc = wave;

    // ---- stage A once (row-major [row][k], chunk slot s holds global chunk s^(row&7))
#pragma unroll
    for (int j = 0; j < 16; ++j) {
        int i = wave * 16 + j;
        int row = i * 2 + (lane >> 5);
        int slot = lane & 31;
        int kc = slot ^ (row & 7);
        const unsigned short* src = ebf + (size_t)(row0 + row) * 256 + kc * 8;
        __builtin_amdgcn_global_load_lds(
            (const __attribute__((address_space(1))) void*)src,
            (__attribute__((address_space(3))) void*)(sA + i * 512), 16, 0, 0);
    }
    asm volatile("s_waitcnt vmcnt(0)" ::: "memory");
    __syncthreads();

    float invd2[8];
    if (PASS == 1) {
#pragma unroll
        for (int mf = 0; mf < 8; ++mf)
            invd2[mf] = denominv[row0 + mf * 16 + l15];
    }
    float es2[8];
    if (PASS == 0) {
#pragma unroll
        for (int mf = 0; mf < 8; ++mf) es2[mf] = 0.f;
    }

    f32x4 zero4 = {0.f, 0.f, 0.f, 0.f};

    for (int ct = cg + 8 * cs; ct < NCT; ct += 16) {
        int mycol0 = ct * 256 + wc * 64;

        // B base pointers (per-lane rows of emb; layout matches frag directly)
        const unsigned short* bp[4];
        int c4[4]; f32x4 bv[4];
#pragma unroll
        for (int nf = 0; nf < 4; ++nf) {
            int gcol = mycol0 + nf * 16 + l15;
            int gcc = (gcol < VOC) ? gcol : (VOC - 1);
            bp[nf] = embbf + (size_t)gcc * 256;
            c4[nf] = mycol0 + nf * 16 + kg * 4;
            if (c4[nf] + 3 < VOC) {
                bv[nf] = *reinterpret_cast<const f32x4u*>(vbias + c4[nf]);
            } else {
#pragma unroll
                for (int r = 0; r < 4; ++r)
                    bv[nf][r] = (c4[nf] + r < VOC) ? vbias[c4[nf] + r] : -1e4f;
            }
        }

        f32x4 acc[8][4];
#pragma unroll
        for (int mf = 0; mf < 8; ++mf)
#pragma unroll
            for (int nf = 0; nf < 4; ++nf) acc[mf][nf] = zero4;

#pragma unroll
        for (int kstep = 0; kstep < 8; ++kstep) {
            bf16x8 b[4];
#pragma unroll
            for (int nf = 0; nf < 4; ++nf)
                b[nf] = *reinterpret_cast<const bf16x8*>(bp[nf] + kstep * 32 + kg * 8);
            bf16x8 a[8];
#pragma unroll
            for (int mf = 0; mf < 8; ++mf) {
                int row = mf * 16 + l15;
                int kc = kstep * 4 + kg;
                a[mf] = *reinterpret_cast<const bf16x8*>(
                    sA + row * 256 + ((kc ^ (row & 7)) * 8));
            }
            // swapped: first operand = b (vocab -> output rows), second = a (token -> output cols)
#pragma unroll
            for (int mf = 0; mf < 8; ++mf)
#pragma unroll
                for (int nf = 0; nf < 4; ++nf)
                    acc[mf][nf] = __builtin_amdgcn_mfma_f32_16x16x32_bf16(
                        b[nf], a[mf], acc[mf][nf], 0, 0, 0);
        }

        if (PASS == 0) {
#pragma unroll
            for (int mf = 0; mf < 8; ++mf) {
                float s = 0.f;
#pragma unroll
                for (int nf = 0; nf < 4; ++nf)
#pragma unroll
                    for (int r = 0; r < 4; ++r)
                        s += __expf(acc[mf][nf][r] + bv[nf][r]);
                es2[mf] += s;
            }
        } else {
#pragma unroll
            for (int mf = 0; mf < 8; ++mf) {
                float* pr = prob + (size_t)(row0 + mf * 16 + l15) * VOC;
#pragma unroll
                for (int nf = 0; nf < 4; ++nf) {
                    if (c4[nf] + 3 < VOC) {
                        f32x4 o;
#pragma unroll
                        for (int r = 0; r < 4; ++r)
                            o[r] = __expf(acc[mf][nf][r] + bv[nf][r]) * invd2[mf];
                        *reinterpret_cast<f32x4u*>(pr + c4[nf]) = o;
                    } else {
#pragma unroll
                        for (int r = 0; r < 4; ++r)
                            if (c4[nf] + r < VOC)
                                pr[c4[nf] + r] =
                                    __expf(acc[mf][nf][r] + bv[nf][r]) * invd2[mf];
                    }
                }
            }
        }
    }

    if (PASS == 0) {
        int slot = (cg * 2 + cs) * 4 + wc;    // 0..63
#pragma unroll
        for (int mf = 0; mf < 8; ++mf) {
            float v = es2[mf];
            v += __shfl_xor(v, 16);
            v += __shfl_xor(v, 32);
            if (kg == 0) {
                int row = row0 + mf * 16 + l15;
                psum[(size_t)slot * NTOK + row] = v;
            }
        }
    }
}

// ---------------------------------------------------------------- finalize: denom + inverse
__global__ __launch_bounds__(256) void finalize_denom(
    const float* __restrict__ psum, float* __restrict__ denom,
    float* __restrict__ denominv) {
    int row = blockIdx.x * 256 + threadIdx.x;
    float s = 0.f;
#pragma unroll
    for (int slot = 0; slot < 64; ++slot) s += psum[(size_t)slot * NTOK + row];
    denom[row] = s;
    denominv[row] = 1.f / s;
}

// ---------------------------------------------------------------- finalize: loss
__global__ __launch_bounds__(64) void finalize_loss(
    const float* __restrict__ denom,
    const unsigned short* __restrict__ ebf, const unsigned short* __restrict__ embbf,
    const float* __restrict__ vbias, const int* __restrict__ labels,
    float* __restrict__ loss) {
    int n = blockIdx.x, lane = threadIdx.x;
    int lf = labels[n];
    const unsigned short* ev = ebf + n * 256;
    const unsigned short* mv = embbf + (size_t)lf * 256;
    float p = 0.f;
#pragma unroll
    for (int i = 0; i < 4; ++i) p += bf2f(ev[lane * 4 + i]) * bf2f(mv[lane * 4 + i]);
#pragma unroll
    for (int off = 1; off < 64; off <<= 1) p += __shfl_xor(p, off);
    if (lane == 0) loss[n] = logf(denom[n]) - (p + vbias[lf]);
}

// ---------------------------------------------------------------- launch
extern "C" void kernel_launch(void* const* d_in, const int* in_sizes, int n_in,
                              void* d_out, int out_size, void* d_ws, size_t ws_size,
                              hipStream_t stream) {
    const float* x      = (const float*)d_in[0];
    const int*   labels = (const int*)d_in[1];
    const int*   xb     = (const int*)d_in[2];
    const float* Wsh    = (const float*)d_in[3];
    const float* bsh    = (const float*)d_in[4];
    const float* Wsp    = (const float*)d_in[5];
    const float* bsp    = (const float*)d_in[6];
    const float* wg     = (const float*)d_in[7];
    const float* vbias  = (const float*)d_in[8];
    const float* emb    = (const float*)d_in[9];
    const float* gamma  = (const float*)d_in[10];
    const float* beta   = (const float*)d_in[11];

    char* ws = (char*)d_ws;
    unsigned short* xbf   = (unsigned short*)(ws + 0);          // 2,097,152
    unsigned short* embbf = (unsigned short*)(ws + 2097152);    // 25,731,584
    unsigned short* Wtbf  = (unsigned short*)(ws + 27828736);   // 1,310,720
    float* cexp           = (float*)(ws + 29360128);            // 41,943,040
    unsigned short* ebf   = (unsigned short*)(ws + 71303168);   // 2,097,152
    float* psum           = (float*)(ws + 73400320);            // 1,048,576
    float* denom          = (float*)(ws + 74448896);            // 16,384
    float* denominv       = (float*)(ws + 74465280);            // 16,384

    float* prob = (float*)d_out;
    float* loss = prob + PROB_ELEMS;

    conv_f32_bf16<<<dim3(512), dim3(256), 0, stream>>>(x, xbf, NTOK * HID / 4);
    conv_f32_bf16<<<dim3(2048), dim3(256), 0, stream>>>(emb, embbf, VOC * HID / 4);
    wt_transpose<<<dim3(40, 4), dim3(256), 0, stream>>>(Wsh, Wsp, Wtbf);
    expert_gemm<<<dim3(64 * 20), dim3(256), 0, stream>>>(xbf, Wtbf, bsh, bsp, cexp);
    combine_ln<<<dim3(NTOK), dim3(256), 0, stream>>>(x, xb, wg, cexp, gamma, beta, ebf);
    vocab_pass<0><<<dim3(512), dim3(256), 0, stream>>>(ebf, embbf, vbias, psum, nullptr, nullptr);
    finalize_denom<<<dim3(16), dim3(256), 0, stream>>>(psum, denom, denominv);
    finalize_loss<<<dim3(NTOK), dim3(64), 0, stream>>>(denom, ebf, embbf, vbias, labels, loss);
    vocab_pass<1><<<dim3(512), dim3(256), 0, stream>>>(ebf, embbf, vbias, nullptr, denominv, prob);
}